// Round 13
// baseline (236.240 us; speedup 1.0000x reference)
//
#include <hip/hip_runtime.h>
#include <hip/hip_fp16.h>

#define NB 2048
#define NC 8
#define NT 1024
#define EPS 1e-5f
#define SLOPE (1.0f/128.0f)
#define NELEM (2048.0f*1024.0f)
#define TB (NT*NB)

// ---- ws layout (floats) ----
// [0, 32768)    : bn1 partials, 2048 slots x 16 (k0 writes, k2 reads; DEAD after k2)
// [0, 128)      : PAR (reservoir params) -- k2 writes AFTER reading all bn1
// [2048, 3392)  : P2 (MFMA frag tables)  -- ditto
// [4096, 49152) : bn2 partials, 2048 slots x 22 (k34 writes into dead bn1 region)
// byte 262144   : xT  fp16 [T][B][8]   (32 MiB)
// byte 262144+32MiB: pre fp16 [11][T][B]  (44 MiB planes)
#define PAR_OFF 0
#define P2_OFF  2048
#define BN2_OFF 4096
// par-relative fp32 indices
#define PF_S4  0
#define PF_O4  8
// packed half2 (index into (unsigned*)par)
#define PU_A4   96
#define XT_BYTE  262144
#define PWS_BYTE (262144 + 2048*1024*8*2)

// LDS row-buffer geometry (halves). ROWH=40 -> 80B rows: 16B-aligned frag reads;
// z is written into rowb cols 16-31 (dead after phase 2) so NO zbuf ->
// LDS/block = 4*64*40*2 = 20480 B exactly -> 8 blocks/CU.
#define ROWH 40

typedef _Float16 h2 __attribute__((ext_vector_type(2)));
typedef _Float16 half8 __attribute__((ext_vector_type(8)));
typedef float f32x4 __attribute__((ext_vector_type(4)));
typedef __fp16  fp16v2 __attribute__((ext_vector_type(2)));
union U32H2 { unsigned u; h2 h; fp16v2 f; unsigned short us[2]; };
union UF { uint4 u; half8 h; };

__device__ __forceinline__ float leaky(float z){ return fmaxf(z, z*SLOPE); }
__device__ __forceinline__ unsigned short f2h(float v){ return __half_as_ushort(__float2half(v)); }
__device__ __forceinline__ float h2f(unsigned short u){ return __half2float(__ushort_as_half(u)); }
__device__ __forceinline__ h2 uph2(unsigned u){ U32H2 x; x.u = u; return x.h; }
__device__ __forceinline__ h2 pk(float a, float b){
    U32H2 x; x.f = __builtin_amdgcn_cvt_pkrtz(a, b); return x.h;   // v_cvt_pkrtz_f16_f32
}
__device__ __forceinline__ h2 leaky2(h2 v){
    h2 s = v * (_Float16)SLOPE;
    return __builtin_elementwise_max(v, s);
}
__device__ __forceinline__ float clamp1(float z){ return __builtin_amdgcn_fmed3f(z, -1.f, 1.f); }
__device__ __forceinline__ unsigned pk2u(float a, float b){
    U32H2 v; v.us[0] = f2h(a); v.us[1] = f2h(b); return v.u;
}

#if defined(__has_builtin)
#if __has_builtin(__builtin_amdgcn_fdot2)
#define HAVE_FDOT2 1
#endif
#endif
#ifdef HAVE_FDOT2
__device__ __forceinline__ float fdot2(h2 a, h2 b, float c){ return __builtin_amdgcn_fdot2(a, b, c, false); }
#else
__device__ __forceinline__ float fdot2(h2 a, h2 b, float c){
    return c + (float)a[0]*(float)b[0] + (float)a[1]*(float)b[1];
}
#endif

// ---------------- K0: BN1 stats + transpose x -> xT[t][b][8] fp16 + zero out ----------------
__global__ __launch_bounds__(256) void k0_tr(const float* __restrict__ x,
                                             unsigned short* __restrict__ xT,
                                             float* __restrict__ ws,
                                             float* __restrict__ out)
{
    __shared__ unsigned short tile[64*134];
    __shared__ float sred[4][4][2];
    const int tid = threadIdx.x;
    const int bg = blockIdx.x >> 4;
    const int tg = blockIdx.x & 15;
    const int b0 = bg*16, t0 = tg*64;
    if(blockIdx.x < 88) out[blockIdx.x*256 + tid] = 0.f;   // 88*256 = 2048*11
    float s = 0.f, s2 = 0.f;
#pragma unroll
    for(int r=0;r<8;r++){
        const int flat4 = r*256 + tid;
        const int row = flat4 >> 4;          // 0..127 = b*8+c
        const int t4  = flat4 & 15;
        const int b = row >> 3, c = row & 7;
        float4 v = *(const float4*)(x + (size_t)(b0+b)*8192 + c*1024 + t0 + t4*4);
        s  += v.x+v.y+v.z+v.w;
        s2 += v.x*v.x+v.y*v.y+v.z*v.z+v.w*v.w;
        const int base = b*8 + c;
        tile[(t4*4+0)*134 + base] = f2h(v.x);
        tile[(t4*4+1)*134 + base] = f2h(v.y);
        tile[(t4*4+2)*134 + base] = f2h(v.z);
        tile[(t4*4+3)*134 + base] = f2h(v.w);
    }
#pragma unroll
    for(int m=8;m>=1;m>>=1){ s += __shfl_xor(s,m,64); s2 += __shfl_xor(s2,m,64); }
    const int lane = tid & 63, wave = tid >> 6;
    if((lane & 15) == 0){ sred[wave][lane>>4][0] = s; sred[wave][lane>>4][1] = s2; }
    __syncthreads();
    if(tid < 16){
        const int c = tid & 7, which = tid >> 3;
        const int w0 = (c < 4) ? 0 : 1, g = c & 3;
        const float v = sred[w0][g][which] + sred[w0+2][g][which];
        ws[blockIdx.x*16 + which*8 + c] = v;     // block-private slot, no atomic/memset
    }
#pragma unroll
    for(int r=0;r<8;r++){
        const int q = r*256 + tid;
        const int t = q >> 5, inner = q & 31;
        const unsigned int lo = *(const unsigned int*)&tile[t*134 + inner*4];
        const unsigned int hi = *(const unsigned int*)&tile[t*134 + inner*4 + 2];
        *(uint2*)(xT + ((size_t)(t0+t)*NB + b0)*8 + inner*4) = make_uint2(lo, hi);
    }
}

// ---------------- K2: finalize BN1 (2048 slots), build params + MFMA frag tables ----------------
// NOTE: PAR/P2 live inside the BN1 region -- safe because ALL BN1 reads complete
// (before the first __syncthreads) before any PAR/P2 write.
__global__ __launch_bounds__(256) void k2_fold(const float* __restrict__ g1, const float* __restrict__ bb1,
    const float* __restrict__ w1, const float* __restrict__ b1,
    const float* __restrict__ w2, const float* __restrict__ b2,
    const float* __restrict__ w3, const float* __restrict__ b3,
    const float* __restrict__ A, float* __restrict__ ws)
{
    float* par = ws + PAR_OFF;
    unsigned* paru = (unsigned*)par;
    __shared__ float red16[16][17];
    __shared__ float st[16];
    __shared__ float ssc[8], soc[8], sb1f[24], sb3f[11];
    const int tid = threadIdx.x;
    {
        const int j = tid & 15, slice = tid >> 4;
        float acc = 0.f;
        for(int i=slice;i<2048;i+=16) acc += ws[i*16 + j];
        red16[slice][j] = acc;
    }
    __syncthreads();
    if(tid<16){
        float s=0.f;
#pragma unroll
        for(int k=0;k<16;k++) s += red16[k][tid];
        st[tid]=s;
    }
    __syncthreads();
    if(tid<8){
        const float inv = 1.0f/NELEM;
        float m  = st[tid]*inv;
        float v  = st[8+tid]*inv - m*m;
        float s_ = g1[tid]*rsqrtf(v+EPS);
        float o_ = bb1[tid] - m*s_;
        ssc[tid]=s_; soc[tid]=o_;
        par[PF_S4+tid]=4.f*s_; par[PF_O4+tid]=4.f*o_;
    }
    __syncthreads();
    if(tid<24){ float a=b1[tid]; for(int c=0;c<8;c++) a += w1[tid*8+c]*soc[c]; sb1f[tid]=a; }
    if(tid<11){ float a=b3[tid]; for(int c=0;c<8;c++) a += w3[tid*48+8+c]*soc[c]; sb3f[tid]=a; }
    if(tid<32){ int i=tid>>2, j=tid&3;
        paru[PU_A4+tid] = pk2u(4.f*A[i*8+2*j], 4.f*A[i*8+2*j+1]); }
    __syncthreads();

    // ---- MFMA fragment tables ----
    // B-frag for v_mfma_f32_16x16x32_f16: lane l holds col n=l&15, k=(l>>4)*8+j.
    unsigned* pt = (unsigned*)(ws + P2_OFF);
    if(tid<64){
        const int n = tid & 15, kq = tid >> 4;
        float v[8];
#pragma unroll
        for(int j=0;j<8;j++){ int k=kq*8+j; v[j] = (k<8)? w1[n*8+k]*ssc[k] : 0.f; }
        for(int j=0;j<4;j++) pt[64 + 0*256 + tid*4 + j] = pk2u(v[2*j], v[2*j+1]);
#pragma unroll
        for(int j=0;j<8;j++){ int k=kq*8+j; int o=16+n;
            v[j] = (o<24 && k<8)? w1[o*8+k]*ssc[k] : 0.f; }
        for(int j=0;j<4;j++) pt[64 + 1*256 + tid*4 + j] = pk2u(v[2*j], v[2*j+1]);
#pragma unroll
        for(int j=0;j<8;j++){ int k=kq*8+j; v[j] = (k<24)? w2[n*24+k] : 0.f; }
        for(int j=0;j<4;j++) pt[64 + 2*256 + tid*4 + j] = pk2u(v[2*j], v[2*j+1]);
#pragma unroll
        for(int j=0;j<8;j++){ int k=kq*8+j;
            float t = 0.f;
            if(n<11){
                if(k<8)       t = w3[n*48+k] + w3[n*48+8+k]*ssc[k];
                else if(k<16) t = w3[n*48+32+(k-8)];
                else if(k<24) t = w3[n*48+40+(k-16)];
            }
            v[j] = t; }
        for(int j=0;j<4;j++) pt[64 + 3*256 + tid*4 + j] = pk2u(v[2*j], v[2*j+1]);
#pragma unroll
        for(int j=0;j<8;j++){ int k=kq*8+j;
            v[j] = (n<11 && k<16)? w3[n*48+16+k] : 0.f; }
        for(int j=0;j<4;j++) pt[64 + 4*256 + tid*4 + j] = pk2u(v[2*j], v[2*j+1]);
    }
    if(tid<16){
        float* bf = ws + P2_OFF;
        bf[tid]      = sb1f[tid];
        bf[16+tid]   = (tid<8)? sb1f[16+tid] : 0.f;
        bf[32+tid]   = b2[tid];
        bf[48+tid]   = (tid<11)? sb3f[tid] : 0.f;
    }
}

// ---------------- K34: reservoir (fdot2) + MFMA FF/W3, 8 blocks/CU ----------------
// grid: 8 bgroups(256 b) x 256 tgroups(4 t) = 2048 blocks. LDS exactly 20480 B
// (zbuf eliminated) -> 8 blocks/CU = 8 waves/SIMD, double r11's residency.
// r10 proved the loop is latency-bound downward (2 waves -> +17%); this tests
// upward. z is written into rowb cols 16-31: dead after phase-2's read (W3B
// weights zero for k>=16), restored by next t's row-write; wave-lockstep
// program order guarantees A3-read-before-z-write within each T-block.
// W=16 warm-up (chunk 4): +67% reservoir work traded for 2x latency hiding.
__global__ __launch_bounds__(256,8) void k34(
    const unsigned short* __restrict__ xT,
    float* __restrict__ ws,
    unsigned short* __restrict__ pws)
{
    const float* par = ws + PAR_OFF;
    const unsigned* pu = (const unsigned*)par;
    const int tid = threadIdx.x;
    const int wave = tid>>6, lane = tid&63;
    const int ln = lane&15, kb = lane>>4;
    const int b  = (blockIdx.x >> 8)*256 + tid;
    const int tg = blockIdx.x & 255;
    const int t0 = tg*4;
    const int tw = (t0 >= 16) ? (t0 - 16) : 0;

    __shared__ unsigned short lds[4*64*ROWH];
    unsigned short* rowb = lds + wave*(64*ROWH);

    // hoist per-lane B-fragments + per-col biases (one-time VMEM)
    const float* p2 = ws + P2_OFF;
    const uint4* ft = (const uint4*)(p2 + 64);
    UF w1a, w1b, w2f, w3a, w3b;
    w1a.u = ft[lane];      w1b.u = ft[64+lane];  w2f.u = ft[128+lane];
    w3a.u = ft[192+lane];  w3b.u = ft[256+lane];
    const float bi1a = p2[ln], bi1b = p2[16+ln], bi2 = p2[32+ln], bi3 = p2[48+ln];

    h2 fh[4];
#pragma unroll
    for(int j=0;j<4;j++) fh[j] = pk(0.f, 0.f);
    float s1 = 0.f, s2 = 0.f;

    // ---- warm-up: reservoir only ----
    for(int t=tw; t<t0; t++){
        union { float4 v; unsigned u[4]; unsigned short us[8]; } ux;
        ux.v = *(const float4*)(xT + ((size_t)t*NB + b)*8);
        float nf[8];
#pragma unroll
        for(int i=0;i<8;i++){
            float acc = fmaf(par[PF_S4+i], h2f(ux.us[i]), par[PF_O4+i]);
#pragma unroll
            for(int j=0;j<4;j++) acc = fdot2(uph2(pu[PU_A4+i*4+j]), fh[j], acc);
            nf[i] = clamp1(acc);
        }
#pragma unroll
        for(int j=0;j<4;j++) fh[j] = pk(nf[2*j], nf[2*j+1]);
    }

    // ---- main: 4 useful t ----
#pragma unroll 2
    for(int t=t0; t<t0+4; ++t){
        union { float4 v; unsigned u[4]; unsigned short us[8]; } ux;
        ux.v = *(const float4*)(xT + ((size_t)t*NB + b)*8);
        float nf[8];
#pragma unroll
        for(int i=0;i<8;i++){
            float acc = fmaf(par[PF_S4+i], h2f(ux.us[i]), par[PF_O4+i]);
#pragma unroll
            for(int j=0;j<4;j++) acc = fdot2(uph2(pu[PU_A4+i*4+j]), fh[j], acc);
            nf[i] = clamp1(acc);
        }
#pragma unroll
        for(int j=0;j<4;j++) fh[j] = pk(nf[2*j], nf[2*j+1]);
        h2 lfh[4];
#pragma unroll
        for(int j=0;j<4;j++) lfh[j] = leaky2(fh[j]);

        // write my row: [x(8) | f(8) | lf(8) | zeros(8)]
        {
            unsigned short* my = rowb + lane*ROWH;
            U32H2 f0,f1,f2,f3, l0,l1,l2,l3;
            f0.h=fh[0]; f1.h=fh[1]; f2.h=fh[2]; f3.h=fh[3];
            l0.h=lfh[0]; l1.h=lfh[1]; l2.h=lfh[2]; l3.h=lfh[3];
            *(uint4*)(my)      = make_uint4(ux.u[0], ux.u[1], ux.u[2], ux.u[3]);
            *(uint4*)(my + 8)  = make_uint4(f0.u, f1.u, f2.u, f3.u);
            *(uint4*)(my + 16) = make_uint4(l0.u, l1.u, l2.u, l3.u);
            *(uint4*)(my + 24) = make_uint4(0u, 0u, 0u, 0u);
        }

        // phase 1: W1a, W1b, W3-part1 from [x|f|lf]; write h (cols 0..31)
        f32x4 accz[4];
#pragma unroll
        for(int T=0;T<4;T++){
            half8 A1 = *(const half8*)(rowb + (T*16+ln)*ROWH + kb*8);
            f32x4 ha = {bi1a, bi1a, bi1a, bi1a};
            f32x4 hb = {bi1b, bi1b, bi1b, bi1b};
            f32x4 zz = {bi3,  bi3,  bi3,  bi3};
            ha = __builtin_amdgcn_mfma_f32_16x16x32_f16(A1, w1a.h, ha, 0,0,0);
            hb = __builtin_amdgcn_mfma_f32_16x16x32_f16(A1, w1b.h, hb, 0,0,0);
            zz = __builtin_amdgcn_mfma_f32_16x16x32_f16(A1, w3a.h, zz, 0,0,0);
            accz[T] = zz;
            unsigned short* hw = rowb + (T*16 + kb*4)*ROWH + ln;
#pragma unroll
            for(int r=0;r<4;r++){
                hw[r*ROWH]      = f2h(leaky(ha[r]));
                hw[r*ROWH + 16] = f2h(leaky(hb[r]));
            }
        }
        // phase 2: W2 from h; write ff (cols 0..15)
#pragma unroll
        for(int T=0;T<4;T++){
            half8 A2 = *(const half8*)(rowb + (T*16+ln)*ROWH + kb*8);
            f32x4 ff = {bi2, bi2, bi2, bi2};
            ff = __builtin_amdgcn_mfma_f32_16x16x32_f16(A2, w2f.h, ff, 0,0,0);
            unsigned short* fw = rowb + (T*16 + kb*4)*ROWH + ln;
#pragma unroll
            for(int r=0;r<4;r++) fw[r*ROWH] = f2h(leaky(ff[r]));
        }
        // phase 3: W3-part2 from ff; s1/s2 + z into rowb cols 16..31
        // (cols 16-31 dead after phase 2; A3 read precedes write in program order)
#pragma unroll
        for(int T=0;T<4;T++){
            half8 A3 = *(const half8*)(rowb + (T*16+ln)*ROWH + kb*8);
            f32x4 zz = __builtin_amdgcn_mfma_f32_16x16x32_f16(A3, w3b.h, accz[T], 0,0,0);
            unsigned short* zw = rowb + (T*16 + kb*4)*ROWH + 16 + ln;
#pragma unroll
            for(int r=0;r<4;r++){
                float z = zz[r];
                s1 += z; s2 = fmaf(z, z, s2);
                zw[r*ROWH] = f2h(z);
            }
        }
        // phase 4: b-coalesced pws stores; z readback 3x b64 from own row
        {
            const size_t base = (size_t)t*NB + b;
            const uint2* mz = (const uint2*)(rowb + lane*ROWH + 16);
            uint2 q0 = mz[0], q1 = mz[1], q2 = mz[2];
            unsigned short zv[12];
            zv[0]=(unsigned short)q0.x;  zv[1]=(unsigned short)(q0.x>>16);
            zv[2]=(unsigned short)q0.y;  zv[3]=(unsigned short)(q0.y>>16);
            zv[4]=(unsigned short)q1.x;  zv[5]=(unsigned short)(q1.x>>16);
            zv[6]=(unsigned short)q1.y;  zv[7]=(unsigned short)(q1.y>>16);
            zv[8]=(unsigned short)q2.x;  zv[9]=(unsigned short)(q2.x>>16);
            zv[10]=(unsigned short)q2.y;
#pragma unroll
            for(int o=0;o<11;o++) pws[(size_t)o*TB + base] = zv[o];
        }
    }

    // BN2 reduction: lane holds plane o=ln partials; sum the 4 kb-groups
    s1 += __shfl_xor(s1, 16, 64); s1 += __shfl_xor(s1, 32, 64);
    s2 += __shfl_xor(s2, 16, 64); s2 += __shfl_xor(s2, 32, 64);
    __shared__ float red[4][22];
    if(kb==0 && ln<11){ red[wave][ln] = s1; red[wave][11+ln] = s2; }
    __syncthreads();
    if(tid<22){
        float tot = red[0][tid]+red[1][tid]+red[2][tid]+red[3][tid];
        ws[BN2_OFF + blockIdx.x*22 + tid] = tot;          // block-private slot
    }
}

// ---------------- K6: fused BN2 finalize + apply + leaky + t-mean ----------------
__global__ __launch_bounds__(256) void k6(const float* __restrict__ g2, const float* __restrict__ bb2,
                                          const float* __restrict__ ws,
                                          const unsigned short* __restrict__ pws,
                                          float* __restrict__ out)
{
    const int o  = blockIdx.x >> 5;
    const int r  = blockIdx.x & 31;
    const int bg = r & 1, tg = r >> 1;
    const int tid = threadIdx.x;

    __shared__ float red[4][2];
    __shared__ float sal, sbe;
    {
        float p1 = 0.f, p2 = 0.f;
        for(int i=tid;i<2048;i+=256){
            p1 += ws[BN2_OFF + i*22 + o];
            p2 += ws[BN2_OFF + i*22 + 11 + o];
        }
#pragma unroll
        for(int m=32;m>=1;m>>=1){ p1 += __shfl_xor(p1,m,64); p2 += __shfl_xor(p2,m,64); }
        const int wave = tid>>6, lane = tid&63;
        if(lane==0){ red[wave][0]=p1; red[wave][1]=p2; }
        __syncthreads();
        if(tid==0){
            float t1 = red[0][0]+red[1][0]+red[2][0]+red[3][0];
            float t2 = red[0][1]+red[1][1]+red[2][1]+red[3][1];
            const float inv = 1.0f/NELEM;
            float m = t1*inv;
            float v = t2*inv - m*m;
            float a = g2[o]*rsqrtf(v+EPS);
            sal = a; sbe = bb2[o] - m*a;
        }
        __syncthreads();
    }
    const float al = sal, be = sbe;

    const int b0 = bg*1024 + tid*4;
    const unsigned short* pp = pws + (size_t)o*TB + b0;
    float acc0=0.f, acc1=0.f, acc2=0.f, acc3=0.f;
#pragma unroll 8
    for(int i=0;i<64;i++){
        const int t = tg*64 + i;
        uint2 u = *(const uint2*)(pp + (size_t)t*NB);
        unsigned short a0 = (unsigned short)(u.x & 0xffff), a1 = (unsigned short)(u.x >> 16);
        unsigned short c0 = (unsigned short)(u.y & 0xffff), c1 = (unsigned short)(u.y >> 16);
        acc0 += leaky(fmaf(al, h2f(a0), be));
        acc1 += leaky(fmaf(al, h2f(a1), be));
        acc2 += leaky(fmaf(al, h2f(c0), be));
        acc3 += leaky(fmaf(al, h2f(c1), be));
    }
    atomicAdd(&out[(b0+0)*11+o], acc0*(1.0f/NT));
    atomicAdd(&out[(b0+1)*11+o], acc1*(1.0f/NT));
    atomicAdd(&out[(b0+2)*11+o], acc2*(1.0f/NT));
    atomicAdd(&out[(b0+3)*11+o], acc3*(1.0f/NT));
}

extern "C" void kernel_launch(void* const* d_in, const int* in_sizes, int n_in,
                              void* d_out, int out_size, void* d_ws, size_t ws_size,
                              hipStream_t stream)
{
    const float* x   = (const float*)d_in[0];
    const float* A   = (const float*)d_in[1];
    const float* g1  = (const float*)d_in[2];
    const float* bb1 = (const float*)d_in[3];
    const float* w1  = (const float*)d_in[4];
    const float* b1  = (const float*)d_in[5];
    const float* w2  = (const float*)d_in[6];
    const float* b2  = (const float*)d_in[7];
    const float* w3  = (const float*)d_in[8];
    const float* b3  = (const float*)d_in[9];
    const float* g2  = (const float*)d_in[10];
    const float* bb2 = (const float*)d_in[11];
    float* out = (float*)d_out;
    float* ws  = (float*)d_ws;
    unsigned short* xT  = (unsigned short*)((char*)d_ws + XT_BYTE);
    unsigned short* pws = (unsigned short*)((char*)d_ws + PWS_BYTE);

    // 4 launches, no memsets: partial slots are block-private (fully overwritten),
    // out zeroed by k0, fold in its own tiny kernel.
    k0_tr  <<<2048, 256, 0, stream>>>(x, xT, ws, out);
    k2_fold<<<1,    256, 0, stream>>>(g1, bb1, w1, b1, w2, b2, w3, b3, A, ws);
    k34    <<<2048, 256, 0, stream>>>(xT, ws, pws);
    k6     <<<352,  256, 0, stream>>>(g2, bb2, ws, pws, out);
}

// Round 14
// 201.230 us; speedup vs baseline: 1.1740x; 1.1740x over previous
//
#include <hip/hip_runtime.h>
#include <hip/hip_fp16.h>

#define NB 2048
#define NC 8
#define NT 1024
#define EPS 1e-5f
#define SLOPE (1.0f/128.0f)
#define NELEM (2048.0f*1024.0f)
#define TB (NT*NB)

// ---- ws layout (floats) ----
// [0, 32768)       : bn1 partials, 2048 slots x 16 (block-private, no memset)
// [32768, 55296)   : bn2 partials, 1024 slots x 22 (block-private, no memset)
// [55296, 56320)   : reservoir params (S4/O4 f32, A4 packed h2)
// [56320, 57664)   : MFMA frag tables (bias[64] f32 + 5 x 64 x uint4 B-frags)
// byte 262144      : xT  fp16 [T][B][8]   (32 MiB)
// byte 262144+32MiB: pre fp16 [11][T][B]  (44 MiB planes)
#define BN2_OFF 32768
#define PAR_OFF 55296
#define P2_OFF  56320
// par-relative fp32 indices
#define PF_S4  0
#define PF_O4  8
// packed half2 (index into (unsigned*)par)
#define PU_A4   96
#define XT_BYTE  262144
#define PWS_BYTE (262144 + 2048*1024*8*2)

// LDS row-buffer geometry (halves). ROWH=40 -> 80B rows, 16B-aligned frag reads.
// ZH=20 -> 40B per lane, 8B-aligned so zbuf readback can use ds_read_b64.
#define ROWH 40
#define ZH   20

typedef _Float16 h2 __attribute__((ext_vector_type(2)));
typedef _Float16 half8 __attribute__((ext_vector_type(8)));
typedef float f32x4 __attribute__((ext_vector_type(4)));
typedef __fp16  fp16v2 __attribute__((ext_vector_type(2)));
union U32H2 { unsigned u; h2 h; fp16v2 f; unsigned short us[2]; };
union UF { uint4 u; half8 h; };

__device__ __forceinline__ float leaky(float z){ return fmaxf(z, z*SLOPE); }
__device__ __forceinline__ unsigned short f2h(float v){ return __half_as_ushort(__float2half(v)); }
__device__ __forceinline__ float h2f(unsigned short u){ return __half2float(__ushort_as_half(u)); }
__device__ __forceinline__ h2 uph2(unsigned u){ U32H2 x; x.u = u; return x.h; }
__device__ __forceinline__ h2 pk(float a, float b){
    U32H2 x; x.f = __builtin_amdgcn_cvt_pkrtz(a, b); return x.h;   // v_cvt_pkrtz_f16_f32
}
__device__ __forceinline__ h2 leaky2(h2 v){
    h2 s = v * (_Float16)SLOPE;
    return __builtin_elementwise_max(v, s);
}
__device__ __forceinline__ float clamp1(float z){ return __builtin_amdgcn_fmed3f(z, -1.f, 1.f); }
__device__ __forceinline__ unsigned pk2u(float a, float b){
    U32H2 v; v.us[0] = f2h(a); v.us[1] = f2h(b); return v.u;
}

#if defined(__has_builtin)
#if __has_builtin(__builtin_amdgcn_fdot2)
#define HAVE_FDOT2 1
#endif
#endif
#ifdef HAVE_FDOT2
__device__ __forceinline__ float fdot2(h2 a, h2 b, float c){ return __builtin_amdgcn_fdot2(a, b, c, false); }
#else
__device__ __forceinline__ float fdot2(h2 a, h2 b, float c){
    return c + (float)a[0]*(float)b[0] + (float)a[1]*(float)b[1];
}
#endif

// ---------------- K0: BN1 stats + transpose x -> xT[t][b][8] fp16 + zero out ----------------
__global__ __launch_bounds__(256) void k0_tr(const float* __restrict__ x,
                                             unsigned short* __restrict__ xT,
                                             float* __restrict__ ws,
                                             float* __restrict__ out)
{
    __shared__ unsigned short tile[64*134];
    __shared__ float sred[4][4][2];
    const int tid = threadIdx.x;
    const int bg = blockIdx.x >> 4;
    const int tg = blockIdx.x & 15;
    const int b0 = bg*16, t0 = tg*64;
    if(blockIdx.x < 88) out[blockIdx.x*256 + tid] = 0.f;   // 88*256 = 2048*11
    float s = 0.f, s2 = 0.f;
#pragma unroll
    for(int r=0;r<8;r++){
        const int flat4 = r*256 + tid;
        const int row = flat4 >> 4;          // 0..127 = b*8+c
        const int t4  = flat4 & 15;
        const int b = row >> 3, c = row & 7;
        float4 v = *(const float4*)(x + (size_t)(b0+b)*8192 + c*1024 + t0 + t4*4);
        s  += v.x+v.y+v.z+v.w;
        s2 += v.x*v.x+v.y*v.y+v.z*v.z+v.w*v.w;
        const int base = b*8 + c;
        tile[(t4*4+0)*134 + base] = f2h(v.x);
        tile[(t4*4+1)*134 + base] = f2h(v.y);
        tile[(t4*4+2)*134 + base] = f2h(v.z);
        tile[(t4*4+3)*134 + base] = f2h(v.w);
    }
#pragma unroll
    for(int m=8;m>=1;m>>=1){ s += __shfl_xor(s,m,64); s2 += __shfl_xor(s2,m,64); }
    const int lane = tid & 63, wave = tid >> 6;
    if((lane & 15) == 0){ sred[wave][lane>>4][0] = s; sred[wave][lane>>4][1] = s2; }
    __syncthreads();
    if(tid < 16){
        const int c = tid & 7, which = tid >> 3;
        const int w0 = (c < 4) ? 0 : 1, g = c & 3;
        const float v = sred[w0][g][which] + sred[w0+2][g][which];
        ws[blockIdx.x*16 + which*8 + c] = v;     // block-private slot, no atomic/memset
    }
#pragma unroll
    for(int r=0;r<8;r++){
        const int q = r*256 + tid;
        const int t = q >> 5, inner = q & 31;
        const unsigned int lo = *(const unsigned int*)&tile[t*134 + inner*4];
        const unsigned int hi = *(const unsigned int*)&tile[t*134 + inner*4 + 2];
        *(uint2*)(xT + ((size_t)(t0+t)*NB + b0)*8 + inner*4) = make_uint2(lo, hi);
    }
}

// ---------------- K2: finalize BN1 (parallel reduce), build params + MFMA frag tables ----------------
// BN1 reduction restructured: r9-r13's version did 128 SERIAL dependent loads on a
// single resident block (whole GPU idle, ~5-10us on the critical path). Now each
// thread issues 32 INDEPENDENT float4 loads (8 slots x 4) then an LDS tree reduce.
__global__ __launch_bounds__(256) void k2_fold(const float* __restrict__ g1, const float* __restrict__ bb1,
    const float* __restrict__ w1, const float* __restrict__ b1,
    const float* __restrict__ w2, const float* __restrict__ b2,
    const float* __restrict__ w3, const float* __restrict__ b3,
    const float* __restrict__ A, float* __restrict__ ws)
{
    float* par = ws + PAR_OFF;
    unsigned* paru = (unsigned*)par;
    __shared__ float4 sred4[256][4];
    __shared__ float ssc[8], soc[8], sb1f[24], sb3f[11];
    const int tid = threadIdx.x;
    {
        float4 a0 = make_float4(0.f,0.f,0.f,0.f), a1 = a0, a2 = a0, a3 = a0;
#pragma unroll
        for(int k=0;k<8;k++){
            const float4* p = (const float4*)(ws + (size_t)(tid + k*256)*16);
            float4 v0 = p[0], v1 = p[1], v2 = p[2], v3 = p[3];
            a0.x+=v0.x; a0.y+=v0.y; a0.z+=v0.z; a0.w+=v0.w;
            a1.x+=v1.x; a1.y+=v1.y; a1.z+=v1.z; a1.w+=v1.w;
            a2.x+=v2.x; a2.y+=v2.y; a2.z+=v2.z; a2.w+=v2.w;
            a3.x+=v3.x; a3.y+=v3.y; a3.z+=v3.z; a3.w+=v3.w;
        }
        sred4[tid][0]=a0; sred4[tid][1]=a1; sred4[tid][2]=a2; sred4[tid][3]=a3;
    }
    __syncthreads();
    for(int off=128;off>=1;off>>=1){
        if(tid<off){
#pragma unroll
            for(int q=0;q<4;q++){
                float4 a = sred4[tid][q], bq = sred4[tid+off][q];
                a.x+=bq.x; a.y+=bq.y; a.z+=bq.z; a.w+=bq.w;
                sred4[tid][q]=a;
            }
        }
        __syncthreads();
    }
    const float* st = (const float*)&sred4[0][0];
    if(tid<8){
        const float inv = 1.0f/NELEM;
        float m  = st[tid]*inv;
        float v  = st[8+tid]*inv - m*m;
        float s_ = g1[tid]*rsqrtf(v+EPS);
        float o_ = bb1[tid] - m*s_;
        ssc[tid]=s_; soc[tid]=o_;
        par[PF_S4+tid]=4.f*s_; par[PF_O4+tid]=4.f*o_;
    }
    __syncthreads();
    if(tid<24){ float a=b1[tid]; for(int c=0;c<8;c++) a += w1[tid*8+c]*soc[c]; sb1f[tid]=a; }
    if(tid<11){ float a=b3[tid]; for(int c=0;c<8;c++) a += w3[tid*48+8+c]*soc[c]; sb3f[tid]=a; }
    if(tid<32){ int i=tid>>2, j=tid&3;
        paru[PU_A4+tid] = pk2u(4.f*A[i*8+2*j], 4.f*A[i*8+2*j+1]); }
    __syncthreads();

    // ---- MFMA fragment tables ----
    // B-frag for v_mfma_f32_16x16x32_f16: lane l holds col n=l&15, k=(l>>4)*8+j.
    unsigned* pt = (unsigned*)(ws + P2_OFF);
    if(tid<64){
        const int n = tid & 15, kq = tid >> 4;
        float v[8];
#pragma unroll
        for(int j=0;j<8;j++){ int k=kq*8+j; v[j] = (k<8)? w1[n*8+k]*ssc[k] : 0.f; }
        for(int j=0;j<4;j++) pt[64 + 0*256 + tid*4 + j] = pk2u(v[2*j], v[2*j+1]);
#pragma unroll
        for(int j=0;j<8;j++){ int k=kq*8+j; int o=16+n;
            v[j] = (o<24 && k<8)? w1[o*8+k]*ssc[k] : 0.f; }
        for(int j=0;j<4;j++) pt[64 + 1*256 + tid*4 + j] = pk2u(v[2*j], v[2*j+1]);
#pragma unroll
        for(int j=0;j<8;j++){ int k=kq*8+j; v[j] = (k<24)? w2[n*24+k] : 0.f; }
        for(int j=0;j<4;j++) pt[64 + 2*256 + tid*4 + j] = pk2u(v[2*j], v[2*j+1]);
#pragma unroll
        for(int j=0;j<8;j++){ int k=kq*8+j;
            float t = 0.f;
            if(n<11){
                if(k<8)       t = w3[n*48+k] + w3[n*48+8+k]*ssc[k];
                else if(k<16) t = w3[n*48+32+(k-8)];
                else if(k<24) t = w3[n*48+40+(k-16)];
            }
            v[j] = t; }
        for(int j=0;j<4;j++) pt[64 + 3*256 + tid*4 + j] = pk2u(v[2*j], v[2*j+1]);
#pragma unroll
        for(int j=0;j<8;j++){ int k=kq*8+j;
            v[j] = (n<11 && k<16)? w3[n*48+16+k] : 0.f; }
        for(int j=0;j<4;j++) pt[64 + 4*256 + tid*4 + j] = pk2u(v[2*j], v[2*j+1]);
    }
    if(tid<16){
        float* bf = ws + P2_OFF;
        bf[tid]      = sb1f[tid];
        bf[16+tid]   = (tid<8)? sb1f[16+tid] : 0.f;
        bf[32+tid]   = b2[tid];
        bf[48+tid]   = (tid<11)? sb3f[tid] : 0.f;
    }
}

// ---------------- K34: reservoir (fdot2) + MFMA FF/W3 (r11-verbatim, 46.5us) ----------------
// grid: 8 bgroups(256 b) x 128 tgroups(8 t) = 1024 blocks, 4 waves/SIMD.
// Chunk/warm-up U-curve measured: chunk16=54us (r10), chunk8=46us (r9/r11),
// chunk4=57us (r13) -> chunk 8 is the minimum; occupancy does not rise with
// smaller LDS (r13), so this is the structural config.
__global__ __launch_bounds__(256,4) void k34(
    const unsigned short* __restrict__ xT,
    float* __restrict__ ws,
    unsigned short* __restrict__ pws)
{
    const float* par = ws + PAR_OFF;
    const unsigned* pu = (const unsigned*)par;
    const int tid = threadIdx.x;
    const int wave = tid>>6, lane = tid&63;
    const int ln = lane&15, kb = lane>>4;
    const int b  = (blockIdx.x >> 7)*256 + tid;
    const int tg = blockIdx.x & 127;
    const int t0 = tg*8;
    const int tw = (t0 >= 16) ? (t0 - 16) : 0;

    __shared__ unsigned short lds[4*64*ROWH + 4*64*ZH];
    unsigned short* rowb = lds + wave*(64*ROWH);
    unsigned short* zbuf = lds + 4*(64*ROWH) + wave*(64*ZH);

    // hoist per-lane B-fragments + per-col biases (one-time VMEM)
    const float* p2 = ws + P2_OFF;
    const uint4* ft = (const uint4*)(p2 + 64);
    UF w1a, w1b, w2f, w3a, w3b;
    w1a.u = ft[lane];      w1b.u = ft[64+lane];  w2f.u = ft[128+lane];
    w3a.u = ft[192+lane];  w3b.u = ft[256+lane];
    const float bi1a = p2[ln], bi1b = p2[16+ln], bi2 = p2[32+ln], bi3 = p2[48+ln];

    h2 fh[4];
#pragma unroll
    for(int j=0;j<4;j++) fh[j] = pk(0.f, 0.f);
    float s1 = 0.f, s2 = 0.f;

    // ---- warm-up: reservoir only ----
    for(int t=tw; t<t0; t++){
        union { float4 v; unsigned u[4]; unsigned short us[8]; } ux;
        ux.v = *(const float4*)(xT + ((size_t)t*NB + b)*8);
        float nf[8];
#pragma unroll
        for(int i=0;i<8;i++){
            float acc = fmaf(par[PF_S4+i], h2f(ux.us[i]), par[PF_O4+i]);
#pragma unroll
            for(int j=0;j<4;j++) acc = fdot2(uph2(pu[PU_A4+i*4+j]), fh[j], acc);
            nf[i] = clamp1(acc);
        }
#pragma unroll
        for(int j=0;j<4;j++) fh[j] = pk(nf[2*j], nf[2*j+1]);
    }

    // ---- main: 8 useful t, unroll 2 for cross-iteration scheduling ----
#pragma unroll 2
    for(int t=t0; t<t0+8; ++t){
        union { float4 v; unsigned u[4]; unsigned short us[8]; } ux;
        ux.v = *(const float4*)(xT + ((size_t)t*NB + b)*8);
        float nf[8];
#pragma unroll
        for(int i=0;i<8;i++){
            float acc = fmaf(par[PF_S4+i], h2f(ux.us[i]), par[PF_O4+i]);
#pragma unroll
            for(int j=0;j<4;j++) acc = fdot2(uph2(pu[PU_A4+i*4+j]), fh[j], acc);
            nf[i] = clamp1(acc);
        }
#pragma unroll
        for(int j=0;j<4;j++) fh[j] = pk(nf[2*j], nf[2*j+1]);
        h2 lfh[4];
#pragma unroll
        for(int j=0;j<4;j++) lfh[j] = leaky2(fh[j]);

        // write my row: [x(8) | f(8) | lf(8) | zeros(8)]
        {
            unsigned short* my = rowb + lane*ROWH;
            U32H2 f0,f1,f2,f3, l0,l1,l2,l3;
            f0.h=fh[0]; f1.h=fh[1]; f2.h=fh[2]; f3.h=fh[3];
            l0.h=lfh[0]; l1.h=lfh[1]; l2.h=lfh[2]; l3.h=lfh[3];
            *(uint4*)(my)      = make_uint4(ux.u[0], ux.u[1], ux.u[2], ux.u[3]);
            *(uint4*)(my + 8)  = make_uint4(f0.u, f1.u, f2.u, f3.u);
            *(uint4*)(my + 16) = make_uint4(l0.u, l1.u, l2.u, l3.u);
            *(uint4*)(my + 24) = make_uint4(0u, 0u, 0u, 0u);
        }

        // phase 1: W1a, W1b, W3-part1 from [x|f|lf]; write h (cols 0..31)
        f32x4 accz[4];
#pragma unroll
        for(int T=0;T<4;T++){
            half8 A1 = *(const half8*)(rowb + (T*16+ln)*ROWH + kb*8);
            f32x4 ha = {bi1a, bi1a, bi1a, bi1a};
            f32x4 hb = {bi1b, bi1b, bi1b, bi1b};
            f32x4 zz = {bi3,  bi3,  bi3,  bi3};
            ha = __builtin_amdgcn_mfma_f32_16x16x32_f16(A1, w1a.h, ha, 0,0,0);
            hb = __builtin_amdgcn_mfma_f32_16x16x32_f16(A1, w1b.h, hb, 0,0,0);
            zz = __builtin_amdgcn_mfma_f32_16x16x32_f16(A1, w3a.h, zz, 0,0,0);
            accz[T] = zz;
            unsigned short* hw = rowb + (T*16 + kb*4)*ROWH + ln;
#pragma unroll
            for(int r=0;r<4;r++){
                hw[r*ROWH]      = f2h(leaky(ha[r]));
                hw[r*ROWH + 16] = f2h(leaky(hb[r]));
            }
        }
        // phase 2: W2 from h; write ff (cols 0..15)
#pragma unroll
        for(int T=0;T<4;T++){
            half8 A2 = *(const half8*)(rowb + (T*16+ln)*ROWH + kb*8);
            f32x4 ff = {bi2, bi2, bi2, bi2};
            ff = __builtin_amdgcn_mfma_f32_16x16x32_f16(A2, w2f.h, ff, 0,0,0);
            unsigned short* fw = rowb + (T*16 + kb*4)*ROWH + ln;
#pragma unroll
            for(int r=0;r<4;r++) fw[r*ROWH] = f2h(leaky(ff[r]));
        }
        // phase 3: W3-part2 from ff; s1/s2 + z->zbuf
#pragma unroll
        for(int T=0;T<4;T++){
            half8 A3 = *(const half8*)(rowb + (T*16+ln)*ROWH + kb*8);
            f32x4 zz = __builtin_amdgcn_mfma_f32_16x16x32_f16(A3, w3b.h, accz[T], 0,0,0);
            unsigned short* zw = zbuf + (T*16 + kb*4)*ZH + ln;
#pragma unroll
            for(int r=0;r<4;r++){
                float z = zz[r];
                s1 += z; s2 = fmaf(z, z, s2);
                zw[r*ZH] = f2h(z);
            }
        }
        // phase 4: b-coalesced pws stores; zbuf readback as 3x b64
        {
            const size_t base = (size_t)t*NB + b;
            const uint2* mz = (const uint2*)(zbuf + lane*ZH);
            uint2 q0 = mz[0], q1 = mz[1], q2 = mz[2];
            unsigned short zv[12];
            zv[0]=(unsigned short)q0.x;  zv[1]=(unsigned short)(q0.x>>16);
            zv[2]=(unsigned short)q0.y;  zv[3]=(unsigned short)(q0.y>>16);
            zv[4]=(unsigned short)q1.x;  zv[5]=(unsigned short)(q1.x>>16);
            zv[6]=(unsigned short)q1.y;  zv[7]=(unsigned short)(q1.y>>16);
            zv[8]=(unsigned short)q2.x;  zv[9]=(unsigned short)(q2.x>>16);
            zv[10]=(unsigned short)q2.y;
#pragma unroll
            for(int o=0;o<11;o++) pws[(size_t)o*TB + base] = zv[o];
        }
    }

    // BN2 reduction: lane holds plane o=ln partials; sum the 4 kb-groups
    s1 += __shfl_xor(s1, 16, 64); s1 += __shfl_xor(s1, 32, 64);
    s2 += __shfl_xor(s2, 16, 64); s2 += __shfl_xor(s2, 32, 64);
    __shared__ float red[4][22];
    if(kb==0 && ln<11){ red[wave][ln] = s1; red[wave][11+ln] = s2; }
    __syncthreads();
    if(tid<22){
        float tot = red[0][tid]+red[1][tid]+red[2][tid]+red[3][tid];
        ws[BN2_OFF + blockIdx.x*22 + tid] = tot;          // block-private slot
    }
}

// ---------------- K6: fused BN2 finalize + apply + leaky + t-mean ----------------
__global__ __launch_bounds__(256) void k6(const float* __restrict__ g2, const float* __restrict__ bb2,
                                          const float* __restrict__ ws,
                                          const unsigned short* __restrict__ pws,
                                          float* __restrict__ out)
{
    const int o  = blockIdx.x >> 5;
    const int r  = blockIdx.x & 31;
    const int bg = r & 1, tg = r >> 1;
    const int tid = threadIdx.x;

    __shared__ float red[4][2];
    __shared__ float sal, sbe;
    {
        float p1 = 0.f, p2 = 0.f;
        for(int i=tid;i<1024;i+=256){
            p1 += ws[BN2_OFF + i*22 + o];
            p2 += ws[BN2_OFF + i*22 + 11 + o];
        }
#pragma unroll
        for(int m=32;m>=1;m>>=1){ p1 += __shfl_xor(p1,m,64); p2 += __shfl_xor(p2,m,64); }
        const int wave = tid>>6, lane = tid&63;
        if(lane==0){ red[wave][0]=p1; red[wave][1]=p2; }
        __syncthreads();
        if(tid==0){
            float t1 = red[0][0]+red[1][0]+red[2][0]+red[3][0];
            float t2 = red[0][1]+red[1][1]+red[2][1]+red[3][1];
            const float inv = 1.0f/NELEM;
            float m = t1*inv;
            float v = t2*inv - m*m;
            float a = g2[o]*rsqrtf(v+EPS);
            sal = a; sbe = bb2[o] - m*a;
        }
        __syncthreads();
    }
    const float al = sal, be = sbe;

    const int b0 = bg*1024 + tid*4;
    const unsigned short* pp = pws + (size_t)o*TB + b0;
    float acc0=0.f, acc1=0.f, acc2=0.f, acc3=0.f;
#pragma unroll 8
    for(int i=0;i<64;i++){
        const int t = tg*64 + i;
        uint2 u = *(const uint2*)(pp + (size_t)t*NB);
        unsigned short a0 = (unsigned short)(u.x & 0xffff), a1 = (unsigned short)(u.x >> 16);
        unsigned short c0 = (unsigned short)(u.y & 0xffff), c1 = (unsigned short)(u.y >> 16);
        acc0 += leaky(fmaf(al, h2f(a0), be));
        acc1 += leaky(fmaf(al, h2f(a1), be));
        acc2 += leaky(fmaf(al, h2f(c0), be));
        acc3 += leaky(fmaf(al, h2f(c1), be));
    }
    atomicAdd(&out[(b0+0)*11+o], acc0*(1.0f/NT));
    atomicAdd(&out[(b0+1)*11+o], acc1*(1.0f/NT));
    atomicAdd(&out[(b0+2)*11+o], acc2*(1.0f/NT));
    atomicAdd(&out[(b0+3)*11+o], acc3*(1.0f/NT));
}

extern "C" void kernel_launch(void* const* d_in, const int* in_sizes, int n_in,
                              void* d_out, int out_size, void* d_ws, size_t ws_size,
                              hipStream_t stream)
{
    const float* x   = (const float*)d_in[0];
    const float* A   = (const float*)d_in[1];
    const float* g1  = (const float*)d_in[2];
    const float* bb1 = (const float*)d_in[3];
    const float* w1  = (const float*)d_in[4];
    const float* b1  = (const float*)d_in[5];
    const float* w2  = (const float*)d_in[6];
    const float* b2  = (const float*)d_in[7];
    const float* w3  = (const float*)d_in[8];
    const float* b3  = (const float*)d_in[9];
    const float* g2  = (const float*)d_in[10];
    const float* bb2 = (const float*)d_in[11];
    float* out = (float*)d_out;
    float* ws  = (float*)d_ws;
    unsigned short* xT  = (unsigned short*)((char*)d_ws + XT_BYTE);
    unsigned short* pws = (unsigned short*)((char*)d_ws + PWS_BYTE);

    // 4 launches, no memsets: partial slots are block-private (fully overwritten),
    // out zeroed by k0, fold in its own (now parallel-reduce) tiny kernel.
    k0_tr  <<<2048, 256, 0, stream>>>(x, xT, ws, out);
    k2_fold<<<1,    256, 0, stream>>>(g1, bb1, w1, b1, w2, b2, w3, b3, A, ws);
    k34    <<<1024, 256, 0, stream>>>(xT, ws, pws);
    k6     <<<352,  256, 0, stream>>>(g2, bb2, ws, pws, out);
}